// Round 4
// baseline (5047.726 us; speedup 1.0000x reference)
//
#include <hip/hip_runtime.h>
#include <math.h>

#define NTH 1024
#define SD 128
#define OD 64
#define PST 132   // row stride (floats) for 128-wide LDS matrices (16B-aligned rows)
#define SST 65    // row stride for 64x64 S/L

// LDS float offsets (kf_seq)
#define OFF_P     0                    // [128][132] P / P_pred ; export: A staging
#define OFF_T     16896                // [128][132]: X temp; then PCtT rows 0..63, KT+qcol rows 64..127
#define OFF_S     33792                // [64][65]  S lower -> L in place
#define OFF_Z     37952                // 128
#define OFF_T1    38080                // 128 (z_pred)
#define OFF_INNOV 38208                // 64
#define OFF_RED   38272                // 64
#define OFF_MISC  38336                // [0]=frozen [1]=hasNaN [2]=valid
#define LDS_FLOATS 38344               // 153.4 KB

// ws float offsets
#define WS_LL    1
#define WS_LOGD  2
#define WS_Z     128
#define WS_KT    1024        // [64][128]  KT[a][i] = K[i][a]
#define WS_SINV  10240       // [64][64]
#define WS_CA    16384       // [64][128]
#define WS_QUAD  24576       // [64] chunk partial quad sums

#define LCH  32
#define WARM 160

#define LOG2PI_F 1.8378770664093453f
#define FREEZE_TOL 1e-5f

__launch_bounds__(NTH)
__global__ void kf_seq(const float* __restrict__ y, const float* __restrict__ A,
                       const float* __restrict__ C, const float* __restrict__ Q,
                       const float* __restrict__ R, const float* __restrict__ z0,
                       const float* __restrict__ P0, float* __restrict__ out,
                       int T, float* __restrict__ wsf, int* __restrict__ wsi) {
  extern __shared__ float lds[];
  const int tid = (int)threadIdx.x;
  const int ti = tid >> 5, tj = tid & 31;
  float* states = out;
  float* cov = out + (size_t)T * SD;

  // ---- init: P <- P0, z <- z0 ----
  for (int p = 0; p < 16; ++p) {
    int idx = tid + p * NTH;
    lds[OFF_P + (idx >> 7) * PST + (idx & 127)] = P0[idx];
  }
  if (tid < SD) lds[OFF_Z + tid] = z0[tid];
  if (tid == 0) { lds[OFF_MISC + 0] = 0.f; lds[OFF_MISC + 1] = 0.f; }
  __syncthreads();

  // ---- global NaN scan of y ----
  {
    int bad = 0;
    int n4 = (T * OD) >> 2;
    for (int idx = tid; idx < n4; idx += NTH) {
      float4 v = ((const float4*)y)[idx];
      if (v.x != v.x || v.y != v.y || v.z != v.z || v.w != v.w) bad = 1;
    }
    if (bad) lds[OFF_MISC + 1] = 1.f;
  }
  __syncthreads();
  const bool hasNaN = (lds[OFF_MISC + 1] != 0.f);

  float llacc = 0.f;      // thread 0
  float logdet_cur = 0.f; // thread 0
  float logdet_step = 0.f;
  int tF = T;

  for (int t = 0; t < T; ++t) {
    if (t > 0) {
      // ---- X = A @ P  (tile i0..i0+3, j0..j0+3) ----
      {
        const int i0 = ti * 4, j0 = tj * 4;
        float acc[4][4] = {};
        for (int k = 0; k < SD; k += 4) {
          float a_[4][4], p_[4][4];
#pragma unroll
          for (int r = 0; r < 4; ++r) {
            float4 v = *(const float4*)&A[(i0 + r) * SD + k];
            a_[r][0] = v.x; a_[r][1] = v.y; a_[r][2] = v.z; a_[r][3] = v.w;
          }
#pragma unroll
          for (int kk = 0; kk < 4; ++kk) {
            float4 v = *(const float4*)&lds[OFF_P + (k + kk) * PST + j0];
            p_[kk][0] = v.x; p_[kk][1] = v.y; p_[kk][2] = v.z; p_[kk][3] = v.w;
          }
#pragma unroll
          for (int r = 0; r < 4; ++r)
#pragma unroll
            for (int c = 0; c < 4; ++c)
#pragma unroll
              for (int kk = 0; kk < 4; ++kk) acc[r][c] += a_[r][kk] * p_[kk][c];
        }
#pragma unroll
        for (int r = 0; r < 4; ++r) {
          float4 v = {acc[r][0], acc[r][1], acc[r][2], acc[r][3]};
          *(float4*)&lds[OFF_T + (i0 + r) * PST + j0] = v;
        }
      }
      __syncthreads();
      // ---- P_pred = X @ A^T + Q  (symmetry of A P A^T); X-row reads broadcast ----
      {
        const int i0 = ti * 4, j0 = tj * 4;
        float acc[4][4] = {};
        for (int k = 0; k < SD; k += 4) {
          float x_[4][4], a_[4][4];
#pragma unroll
          for (int r = 0; r < 4; ++r) {
            float4 v = *(const float4*)&lds[OFF_T + (i0 + r) * PST + k];
            x_[r][0] = v.x; x_[r][1] = v.y; x_[r][2] = v.z; x_[r][3] = v.w;
          }
#pragma unroll
          for (int c = 0; c < 4; ++c) {
            float4 v = *(const float4*)&A[(j0 + c) * SD + k];
            a_[c][0] = v.x; a_[c][1] = v.y; a_[c][2] = v.z; a_[c][3] = v.w;
          }
#pragma unroll
          for (int r = 0; r < 4; ++r)
#pragma unroll
            for (int c = 0; c < 4; ++c)
#pragma unroll
              for (int kk = 0; kk < 4; ++kk) acc[r][c] += x_[r][kk] * a_[c][kk];
        }
#pragma unroll
        for (int r = 0; r < 4; ++r) {
          float4 q4 = *(const float4*)&Q[(i0 + r) * SD + j0];
          float4 v = {acc[r][0] + q4.x, acc[r][1] + q4.y,
                      acc[r][2] + q4.z, acc[r][3] + q4.w};
          *(float4*)&lds[OFF_P + (i0 + r) * PST + j0] = v;
        }
      }
      // ---- z_pred = A @ z ----
      {
        int i = tid >> 3, s = tid & 7;
        float sum = 0.f;
        for (int kk = 0; kk < 16; ++kk) {
          int k = s * 16 + kk;
          sum += A[i * SD + k] * lds[OFF_Z + k];
        }
        sum += __shfl_xor(sum, 1);
        sum += __shfl_xor(sum, 2);
        sum += __shfl_xor(sum, 4);
        if (s == 0) lds[OFF_T1 + i] = sum;
      }
      if (tid == 0) lds[OFF_MISC + 2] = 1.f;
      __syncthreads();
    } else {
      if (tid < SD) lds[OFF_T1 + tid] = lds[OFF_Z + tid];
      if (tid == 0) lds[OFF_MISC + 2] = 1.f;
      __syncthreads();
    }

    // ---- PCtT = C @ P_pred  [64][128] into OFF_T rows 0..63; NaN check ----
    {
      const int a0 = ti * 2, i0 = tj * 4;
      float acc[2][4] = {};
      for (int m = 0; m < SD; m += 4) {
        float c_[2][4], p_[4][4];
#pragma unroll
        for (int r = 0; r < 2; ++r) {
          float4 v = *(const float4*)&C[(a0 + r) * SD + m];
          c_[r][0] = v.x; c_[r][1] = v.y; c_[r][2] = v.z; c_[r][3] = v.w;
        }
#pragma unroll
        for (int mm = 0; mm < 4; ++mm) {
          float4 v = *(const float4*)&lds[OFF_P + (m + mm) * PST + i0];
          p_[mm][0] = v.x; p_[mm][1] = v.y; p_[mm][2] = v.z; p_[mm][3] = v.w;
        }
#pragma unroll
        for (int r = 0; r < 2; ++r)
#pragma unroll
          for (int c = 0; c < 4; ++c)
#pragma unroll
            for (int mm = 0; mm < 4; ++mm) acc[r][c] += c_[r][mm] * p_[mm][c];
      }
#pragma unroll
      for (int r = 0; r < 2; ++r) {
        float4 v = {acc[r][0], acc[r][1], acc[r][2], acc[r][3]};
        *(float4*)&lds[OFF_T + (a0 + r) * PST + i0] = v;
      }
      if (tid < OD) {
        float yv = y[(size_t)t * OD + tid];
        if (yv != yv) lds[OFF_MISC + 2] = 0.f;
      }
    }
    __syncthreads();

    // ---- S = C P_pred C^T + R + jit = PCtT[a][:] . C[b][:]
    //      rows a0,a0+1 from LDS (broadcast), C rows tj,tj+32 from global ----
    {
      const int a0 = ti * 2;
      float acc[2][2] = {};
      for (int k = 0; k < SD; k += 4) {
        float pa_[2][4], cb_[2][4];
#pragma unroll
        for (int r = 0; r < 2; ++r) {
          float4 v = *(const float4*)&lds[OFF_T + (a0 + r) * PST + k];
          pa_[r][0] = v.x; pa_[r][1] = v.y; pa_[r][2] = v.z; pa_[r][3] = v.w;
        }
#pragma unroll
        for (int cb = 0; cb < 2; ++cb) {
          float4 v = *(const float4*)&C[(tj + 32 * cb) * SD + k];
          cb_[cb][0] = v.x; cb_[cb][1] = v.y; cb_[cb][2] = v.z; cb_[cb][3] = v.w;
        }
#pragma unroll
        for (int r = 0; r < 2; ++r)
#pragma unroll
          for (int cb = 0; cb < 2; ++cb)
#pragma unroll
            for (int kk = 0; kk < 4; ++kk) acc[r][cb] += pa_[r][kk] * cb_[cb][kk];
      }
#pragma unroll
      for (int r = 0; r < 2; ++r)
#pragma unroll
        for (int cb = 0; cb < 2; ++cb) {
          int a = a0 + r, b = tj + 32 * cb;
          lds[OFF_S + a * SST + b] =
              acc[r][cb] + R[a * OD + b] + ((a == b) ? 1e-6f : 0.f);
        }
    }
    // ---- innov = y_safe - C z_pred ----
    if (tid < 512) {
      int o = tid >> 3, s = tid & 7;
      float sum = 0.f;
      for (int kk = 0; kk < 16; ++kk) {
        int k = s * 16 + kk;
        sum += C[o * SD + k] * lds[OFF_T1 + k];
      }
      sum += __shfl_xor(sum, 1);
      sum += __shfl_xor(sum, 2);
      sum += __shfl_xor(sum, 4);
      if (s == 0) {
        float yv = y[(size_t)t * OD + o];
        if (yv != yv) yv = 0.f;
        lds[OFF_INNOV + o] = yv - sum;
      }
    }
    __syncthreads();

    // ---- single-wave in-place Cholesky (wave 0, lockstep, no s_barrier) ----
    logdet_step = 0.f;
    if (tid < 64) {
      const int i = tid;
      for (int j = 0; j < OD; ++j) {
        float p = lds[OFF_S + j * SST + j];
        float inv = 1.0f / p;
        float sij = (i > j) ? lds[OFF_S + i * SST + j] : 0.f;
        for (int k = j + 1; k <= i; ++k) {
          float skj = lds[OFF_S + k * SST + j];   // broadcast
          lds[OFF_S + i * SST + k] -= sij * skj * inv;
        }
        __builtin_amdgcn_wave_barrier();
        if (i > j) lds[OFF_S + i * SST + j] = sij * rsqrtf(p);
        else if (i == j) lds[OFF_S + j * SST + j] = sqrtf(p);
        if (i == 0) logdet_step += logf(p);
        __builtin_amdgcn_wave_barrier();
      }
    }
    __syncthreads();

    // ---- solve S X = [PCtT | innov]: per-column fwd+bwd substitution (no barriers)
    //      result rows 64..127 of OFF_T: KT[a][i] (cols 0..127), S^-1 innov (col 128)
    if (tid < 129) {
      const int c = tid;
      const int xb = OFF_T + 64 * PST + c;
      for (int i = 0; i < OD; ++i) {
        float s0 = (c < SD) ? lds[OFF_T + i * PST + c] : lds[OFF_INNOV + i];
        float s1 = 0.f;
        int j = 0;
        for (; j + 1 < i; j += 2) {
          s0 -= lds[OFF_S + i * SST + j]     * lds[xb + j * PST];
          s1 -= lds[OFF_S + i * SST + j + 1] * lds[xb + (j + 1) * PST];
        }
        if (j < i) s0 -= lds[OFF_S + i * SST + j] * lds[xb + j * PST];
        lds[xb + i * PST] = (s0 + s1) / lds[OFF_S + i * SST + i];
      }
      for (int i = OD - 1; i >= 0; --i) {
        float s0 = lds[xb + i * PST];
        float s1 = 0.f;
        int j = i + 1;
        for (; j + 1 < OD; j += 2) {
          s0 -= lds[OFF_S + j * SST + i]       * lds[xb + j * PST];
          s1 -= lds[OFF_S + (j + 1) * SST + i] * lds[xb + (j + 1) * PST];
        }
        if (j < OD) s0 -= lds[OFF_S + j * SST + i] * lds[xb + j * PST];
        lds[xb + i * PST] = (s0 + s1) / lds[OFF_S + i * SST + i];
      }
    }
    __syncthreads();

    const bool valid = (lds[OFF_MISC + 2] != 0.f);
    // ---- quad + ll (wave 0) ----
    if (tid < 64) {
      float q = lds[OFF_INNOV + tid] * lds[OFF_T + (64 + tid) * PST + 128];
      q += __shfl_xor(q, 1);  q += __shfl_xor(q, 2);  q += __shfl_xor(q, 4);
      q += __shfl_xor(q, 8);  q += __shfl_xor(q, 16); q += __shfl_xor(q, 32);
      if (tid == 0) {
        logdet_cur = logdet_step;
        if (valid) llacc += -0.5f * (logdet_step + q + OD * LOG2PI_F);
      }
    }
    // ---- z update ----
    {
      int i = tid >> 3, s = tid & 7;
      float sum = 0.f;
      for (int kk = 0; kk < 8; ++kk) {
        int k = s * 8 + kk;
        sum += lds[OFF_T + (64 + k) * PST + i] * lds[OFF_INNOV + k];
      }
      sum += __shfl_xor(sum, 1);
      sum += __shfl_xor(sum, 2);
      sum += __shfl_xor(sum, 4);
      if (s == 0) {
        float zi = lds[OFF_T1 + i] + (valid ? sum : 0.f);
        lds[OFF_Z + i] = zi;
        states[(size_t)t * SD + i] = zi;
      }
    }
    // ---- P_u = P_pred - KT^T @ PCtT ----
    {
      const int i0 = ti * 4, j0 = tj * 4;
      float acc[4][4] = {};
      for (int a = 0; a < OD; ++a) {
        float4 kt4 = *(const float4*)&lds[OFF_T + (64 + a) * PST + i0];  // broadcast
        float4 pc4 = *(const float4*)&lds[OFF_T + a * PST + j0];
        float kt_[4] = {kt4.x, kt4.y, kt4.z, kt4.w};
        float pc_[4] = {pc4.x, pc4.y, pc4.z, pc4.w};
#pragma unroll
        for (int r = 0; r < 4; ++r)
#pragma unroll
          for (int c = 0; c < 4; ++c) acc[r][c] += kt_[r] * pc_[c];
      }
      if (valid) {
#pragma unroll
        for (int r = 0; r < 4; ++r) {
          float4 v = *(const float4*)&lds[OFF_P + (i0 + r) * PST + j0];
          v.x -= acc[r][0]; v.y -= acc[r][1]; v.z -= acc[r][2]; v.w -= acc[r][3];
          *(float4*)&lds[OFF_P + (i0 + r) * PST + j0] = v;
        }
      }
    }
    __syncthreads();

    // ---- write cov[t], convergence check ----
    {
      float maxd = 0.f;
      float* covt = cov + (size_t)t * SD * SD;
      const float4* covp = (const float4*)(cov + (size_t)(t - 1) * SD * SD);
#pragma unroll
      for (int p = 0; p < 4; ++p) {
        int idx = tid + p * NTH;               // 4096 float4s
        int i = idx >> 5, j = (idx & 31) * 4;
        float4 v = *(const float4*)&lds[OFF_P + i * PST + j];
        ((float4*)covt)[idx] = v;
        if (t > 0 && !hasNaN) {
          float4 pv = covp[idx];
          maxd = fmaxf(maxd, fmaxf(fmaxf(fabsf(v.x - pv.x), fabsf(v.y - pv.y)),
                                   fmaxf(fabsf(v.z - pv.z), fabsf(v.w - pv.w))));
        }
      }
      for (int m = 1; m < 64; m <<= 1) maxd = fmaxf(maxd, __shfl_xor(maxd, m));
      if ((tid & 63) == 0) lds[OFF_RED + (tid >> 6)] = maxd;
    }
    __syncthreads();
    if (tid == 0) {
      float md = 0.f;
      for (int w = 0; w < 16; ++w) md = fmaxf(md, lds[OFF_RED + w]);
      if (t > 0 && !hasNaN && md < FREEZE_TOL) lds[OFF_MISC + 0] = 1.f;
    }
    __syncthreads();
    if (lds[OFF_MISC + 0] != 0.f) { tF = t + 1; break; }
    __syncthreads();
  }

  // ---- export steady-state data ----
  if (tid == 0) {
    wsi[0] = tF;
    wsf[WS_LL] = llacc;
    wsf[WS_LOGD] = logdet_cur;
  }
  if (tid < SD) wsf[WS_Z + tid] = lds[OFF_Z + tid];
  if (tF < T) {
    // KT -> ws (before Sinv solve reuses the region)
    for (int p = 0; p < 8; ++p) {
      int idx = tid + p * NTH;
      int a = idx >> 7, i2 = idx & 127;
      wsf[WS_KT + idx] = lds[OFF_T + (64 + a) * PST + i2];
    }
    __syncthreads();
    // Sinv = solve(S, I) per column (threads 0..63)
    if (tid < 64) {
      const int c = tid;
      const int xb = OFF_T + 64 * PST + c;
      for (int i = 0; i < OD; ++i) {
        float s0 = (i == c) ? 1.f : 0.f;
        for (int j = 0; j < i; ++j)
          s0 -= lds[OFF_S + i * SST + j] * lds[xb + j * PST];
        lds[xb + i * PST] = s0 / lds[OFF_S + i * SST + i];
      }
      for (int i = OD - 1; i >= 0; --i) {
        float s0 = lds[xb + i * PST];
        for (int j = i + 1; j < OD; ++j)
          s0 -= lds[OFF_S + j * SST + i] * lds[xb + j * PST];
        float xi = s0 / lds[OFF_S + i * SST + i];
        lds[xb + i * PST] = xi;
        wsf[WS_SINV + i * OD + c] = xi;
      }
    }
    __syncthreads();
    // stage A, compute CA = C @ A
    for (int p = 0; p < 16; ++p) {
      int idx = tid + p * NTH;
      lds[OFF_P + (idx >> 7) * PST + (idx & 127)] = A[idx];
    }
    __syncthreads();
    {
      const int a0 = ti * 2, k0 = tj * 4;
      float acc[2][4] = {};
      for (int m = 0; m < SD; m += 4) {
        float c_[2][4], a_[4][4];
#pragma unroll
        for (int r = 0; r < 2; ++r) {
          float4 v = *(const float4*)&C[(a0 + r) * SD + m];
          c_[r][0] = v.x; c_[r][1] = v.y; c_[r][2] = v.z; c_[r][3] = v.w;
        }
#pragma unroll
        for (int mm = 0; mm < 4; ++mm) {
          float4 v = *(const float4*)&lds[OFF_P + (m + mm) * PST + k0];
          a_[mm][0] = v.x; a_[mm][1] = v.y; a_[mm][2] = v.z; a_[mm][3] = v.w;
        }
#pragma unroll
        for (int r = 0; r < 2; ++r)
#pragma unroll
          for (int cc = 0; cc < 4; ++cc)
#pragma unroll
            for (int mm = 0; mm < 4; ++mm) acc[r][cc] += c_[r][mm] * a_[mm][cc];
      }
#pragma unroll
      for (int r = 0; r < 2; ++r)
#pragma unroll
        for (int cc = 0; cc < 4; ++cc)
          wsf[WS_CA + (a0 + r) * SD + k0 + cc] = acc[r][cc];
    }
  }
}

// Parallel frozen-phase recursion (unchanged)
__launch_bounds__(512, 1)
__global__ void kf_chunk(const float* __restrict__ y, const float* __restrict__ A,
                         const float* __restrict__ wsf, const int* __restrict__ wsi,
                         float* __restrict__ out, int T) {
  __shared__ __align__(16) float zv[SD];
  __shared__ __align__(16) float vv[192];
  __shared__ __align__(16) float yb[2][OD];
  __shared__ float red[8];
  const int tid = (int)threadIdx.x;
  const int c = (int)blockIdx.x;
  const int tF = wsi[0];
  float* states = out;
  float* quad_out = (float*)wsf + WS_QUAD;

  int t_end = (c + 1) * LCH; if (t_end > T) t_end = T;
  int t_begin = c * LCH; if (t_begin < tF) t_begin = tF;
  float qacc = 0.f;

  if (t_begin < t_end) {
    int s0 = t_begin - WARM; if (s0 < tF) s0 = tF;
    const int r = tid >> 1, h = tid & 1;
    const int ki = tid >> 2, kq = tid & 3;
    const int so = tid >> 3, se = tid & 7;

    float G[64];
    if (tid < 384) {
      const float* src = (r < SD) ? (A + r * SD + h * 64)
                                  : (wsf + WS_CA + (r - SD) * SD + h * 64);
#pragma unroll
      for (int k = 0; k < 16; ++k) {
        float4 g4 = ((const float4*)src)[k];
        G[4 * k + 0] = g4.x; G[4 * k + 1] = g4.y;
        G[4 * k + 2] = g4.z; G[4 * k + 3] = g4.w;
      }
    }
    float K[16];
#pragma unroll
    for (int k = 0; k < 16; ++k) K[k] = wsf[WS_KT + (kq * 16 + k) * SD + ki];
    float Sv[8];
#pragma unroll
    for (int k = 0; k < 8; ++k) Sv[k] = wsf[WS_SINV + so * OD + se * 8 + k];

    if (tid < SD) zv[tid] = (s0 == tF) ? wsf[WS_Z + tid] : 0.f;
    if (tid < OD) yb[s0 & 1][tid] = y[(size_t)s0 * OD + tid];
    __syncthreads();

    for (int t = s0; t < t_end; ++t) {
      if (tid < 384) {
        const float* zz = zv + h * 64;
        float sum = 0.f;
#pragma unroll
        for (int k = 0; k < 16; ++k) {
          float4 z4 = ((const float4*)zz)[k];
          sum += G[4 * k + 0] * z4.x + G[4 * k + 1] * z4.y +
                 G[4 * k + 2] * z4.z + G[4 * k + 3] * z4.w;
        }
        sum += __shfl_xor(sum, 1);
        if (h == 0) vv[r] = sum;
      } else if (tid >= 448) {
        int o = tid - 448;
        if (t + 1 < t_end) yb[(t + 1) & 1][o] = y[(size_t)(t + 1) * OD + o];
      }
      __syncthreads();
      const float* ybt = yb[t & 1];
      {
        const int a0 = kq * 16;
        float sum = 0.f;
#pragma unroll
        for (int k4 = 0; k4 < 4; ++k4) {
          float4 y4 = ((const float4*)(ybt + a0))[k4];
          float4 v4 = ((const float4*)(vv + SD + a0))[k4];
          sum += K[4 * k4 + 0] * (y4.x - v4.x) + K[4 * k4 + 1] * (y4.y - v4.y) +
                 K[4 * k4 + 2] * (y4.z - v4.z) + K[4 * k4 + 3] * (y4.w - v4.w);
        }
        sum += __shfl_xor(sum, 1);
        sum += __shfl_xor(sum, 2);
        if (kq == 0) {
          float zi = vv[ki] + sum;
          zv[ki] = zi;
          if (t >= t_begin) states[(size_t)t * SD + ki] = zi;
        }
      }
      if (t >= t_begin) {
        const int b0 = se * 8;
        float sp = 0.f;
#pragma unroll
        for (int k4 = 0; k4 < 2; ++k4) {
          float4 y4 = ((const float4*)(ybt + b0))[k4];
          float4 v4 = ((const float4*)(vv + SD + b0))[k4];
          sp += Sv[4 * k4 + 0] * (y4.x - v4.x) + Sv[4 * k4 + 1] * (y4.y - v4.y) +
                Sv[4 * k4 + 2] * (y4.z - v4.z) + Sv[4 * k4 + 3] * (y4.w - v4.w);
        }
        qacc += sp * (ybt[so] - vv[SD + so]);
      }
      __syncthreads();
    }
  }

  float q = qacc;
  for (int m = 1; m < 64; m <<= 1) q += __shfl_xor(q, m);
  if ((tid & 63) == 0) red[tid >> 6] = q;
  __syncthreads();
  if (tid == 0) {
    float s = 0.f;
    for (int w = 0; w < 8; ++w) s += red[w];
    quad_out[c] = s;
  }
}

__global__ void kf_ll(const float* __restrict__ wsf, const int* __restrict__ wsi,
                      float* __restrict__ out, int T, int nchunks) {
  if (threadIdx.x == 0 && blockIdx.x == 0) {
    int tF = wsi[0];
    float ll = wsf[WS_LL];
    if (tF < T) {
      float qs = 0.f;
      for (int c = 0; c < nchunks; ++c) qs += wsf[WS_QUAD + c];
      ll += -0.5f * (qs + (float)(T - tF) * (wsf[WS_LOGD] + (float)OD * LOG2PI_F));
    }
    out[(size_t)T * SD + (size_t)T * SD * SD] = ll;
  }
}

__global__ void kf_fill(float* __restrict__ cov, const int* __restrict__ ws_tf, int T) {
  int t = (int)blockIdx.x;
  int tF = ws_tf[0];
  if (t < tF) return;
  const float4* src = (const float4*)(cov + (size_t)(tF - 1) * SD * SD);
  float4* dst = (float4*)(cov + (size_t)t * SD * SD);
#pragma unroll
  for (int p = 0; p < 16; ++p) {
    int idx = (int)threadIdx.x + p * 256;
    dst[idx] = src[idx];
  }
}

extern "C" void kernel_launch(void* const* d_in, const int* in_sizes, int n_in,
                              void* d_out, int out_size, void* d_ws, size_t ws_size,
                              hipStream_t stream) {
  const float* y  = (const float*)d_in[0];
  const float* A  = (const float*)d_in[1];
  const float* C  = (const float*)d_in[2];
  const float* Q  = (const float*)d_in[3];
  const float* R  = (const float*)d_in[4];
  const float* z0 = (const float*)d_in[5];
  const float* P0 = (const float*)d_in[6];
  float* out = (float*)d_out;
  int T = in_sizes[0] / OD;
  float* wsf = (float*)d_ws;
  int* wsi = (int*)d_ws;

  size_t ldsBytes = (size_t)LDS_FLOATS * sizeof(float);
  (void)hipFuncSetAttribute((const void*)kf_seq,
                            hipFuncAttributeMaxDynamicSharedMemorySize,
                            (int)ldsBytes);

  kf_seq<<<dim3(1), dim3(NTH), ldsBytes, stream>>>(y, A, C, Q, R, z0, P0, out, T, wsf, wsi);

  int nch = (T + LCH - 1) / LCH;
  kf_chunk<<<dim3(nch), dim3(512), 0, stream>>>(y, A, wsf, wsi, out, T);
  kf_ll<<<dim3(1), dim3(64), 0, stream>>>(wsf, wsi, out, T, nch);

  float* cov = out + (size_t)T * SD;
  kf_fill<<<dim3(T), dim3(256), 0, stream>>>(cov, wsi, T);
}

// Round 5
// 4243.410 us; speedup vs baseline: 1.1895x; 1.1895x over previous
//
#include <hip/hip_runtime.h>
#include <math.h>

#define NTH 1024
#define SD 128
#define OD 64
#define PST 132   // row stride (floats) for 128-wide LDS matrices (16B-aligned rows)
#define SST 65    // row stride for 64x64 S/L

// LDS float offsets (kf_seq)
#define OFF_P     0                    // [128][132] P / P_pred ; export: A staging
#define OFF_T     16896                // [128][132]: X temp; then PCtT rows 0..63, KT+qcol rows 64..127
#define OFF_S     33792                // [64][65]  S lower -> L in place
#define OFF_Z     37952                // 128
#define OFF_T1    38080                // 128 (z_pred)
#define OFF_INNOV 38208                // 64
#define OFF_RED   38272                // 64
#define OFF_MISC  38336                // [0]=frozen [1]=hasNaN [2]=valid
#define LDS_FLOATS 38344               // 153.4 KB

// ws float offsets
#define WS_LL    1
#define WS_LOGD  2
#define WS_Z     128
#define WS_KT    1024        // [64][128]  KT[a][i] = K[i][a]
#define WS_SINV  10240       // [64][64]
#define WS_CA    16384       // [64][128]
#define WS_QUAD  24576       // [64] chunk partial quad sums

#define LCH  32
#define WARM 160

#define LOG2PI_F 1.8378770664093453f
#define FREEZE_TOL 1e-4f

__launch_bounds__(NTH)
__global__ void kf_seq(const float* __restrict__ y, const float* __restrict__ A,
                       const float* __restrict__ C, const float* __restrict__ Q,
                       const float* __restrict__ R, const float* __restrict__ z0,
                       const float* __restrict__ P0, float* __restrict__ out,
                       int T, float* __restrict__ wsf, int* __restrict__ wsi) {
  extern __shared__ float lds[];
  const int tid = (int)threadIdx.x;
  const int ti = tid >> 5, tj = tid & 31;
  float* states = out;
  float* cov = out + (size_t)T * SD;

  // ---- init: P <- P0, z <- z0 ----
  for (int p = 0; p < 16; ++p) {
    int idx = tid + p * NTH;
    lds[OFF_P + (idx >> 7) * PST + (idx & 127)] = P0[idx];
  }
  if (tid < SD) lds[OFF_Z + tid] = z0[tid];
  if (tid == 0) { lds[OFF_MISC + 0] = 0.f; lds[OFF_MISC + 1] = 0.f; }
  __syncthreads();

  // ---- global NaN scan of y ----
  {
    int bad = 0;
    int n4 = (T * OD) >> 2;
    for (int idx = tid; idx < n4; idx += NTH) {
      float4 v = ((const float4*)y)[idx];
      if (v.x != v.x || v.y != v.y || v.z != v.z || v.w != v.w) bad = 1;
    }
    if (bad) lds[OFF_MISC + 1] = 1.f;
  }
  __syncthreads();
  const bool hasNaN = (lds[OFF_MISC + 1] != 0.f);

  float llacc = 0.f;      // thread 0
  float logdet_cur = 0.f; // thread 0
  float logdet_step = 0.f;
  int tF = T;

  for (int t = 0; t < T; ++t) {
    if (t > 0) {
      // ---- X = A @ P  (tile i0..i0+3, j0..j0+3) ----
      {
        const int i0 = ti * 4, j0 = tj * 4;
        float acc[4][4] = {};
        for (int k = 0; k < SD; k += 4) {
          float a_[4][4], p_[4][4];
#pragma unroll
          for (int r = 0; r < 4; ++r) {
            float4 v = *(const float4*)&A[(i0 + r) * SD + k];
            a_[r][0] = v.x; a_[r][1] = v.y; a_[r][2] = v.z; a_[r][3] = v.w;
          }
#pragma unroll
          for (int kk = 0; kk < 4; ++kk) {
            float4 v = *(const float4*)&lds[OFF_P + (k + kk) * PST + j0];
            p_[kk][0] = v.x; p_[kk][1] = v.y; p_[kk][2] = v.z; p_[kk][3] = v.w;
          }
#pragma unroll
          for (int r = 0; r < 4; ++r)
#pragma unroll
            for (int c = 0; c < 4; ++c)
#pragma unroll
              for (int kk = 0; kk < 4; ++kk) acc[r][c] += a_[r][kk] * p_[kk][c];
        }
#pragma unroll
        for (int r = 0; r < 4; ++r) {
          float4 v = {acc[r][0], acc[r][1], acc[r][2], acc[r][3]};
          *(float4*)&lds[OFF_T + (i0 + r) * PST + j0] = v;
        }
      }
      __syncthreads();
      // ---- P_pred = X @ A^T + Q  (symmetry of A P A^T); X-row reads broadcast ----
      {
        const int i0 = ti * 4, j0 = tj * 4;
        float acc[4][4] = {};
        for (int k = 0; k < SD; k += 4) {
          float x_[4][4], a_[4][4];
#pragma unroll
          for (int r = 0; r < 4; ++r) {
            float4 v = *(const float4*)&lds[OFF_T + (i0 + r) * PST + k];
            x_[r][0] = v.x; x_[r][1] = v.y; x_[r][2] = v.z; x_[r][3] = v.w;
          }
#pragma unroll
          for (int c = 0; c < 4; ++c) {
            float4 v = *(const float4*)&A[(j0 + c) * SD + k];
            a_[c][0] = v.x; a_[c][1] = v.y; a_[c][2] = v.z; a_[c][3] = v.w;
          }
#pragma unroll
          for (int r = 0; r < 4; ++r)
#pragma unroll
            for (int c = 0; c < 4; ++c)
#pragma unroll
              for (int kk = 0; kk < 4; ++kk) acc[r][c] += x_[r][kk] * a_[c][kk];
        }
#pragma unroll
        for (int r = 0; r < 4; ++r) {
          float4 q4 = *(const float4*)&Q[(i0 + r) * SD + j0];
          float4 v = {acc[r][0] + q4.x, acc[r][1] + q4.y,
                      acc[r][2] + q4.z, acc[r][3] + q4.w};
          *(float4*)&lds[OFF_P + (i0 + r) * PST + j0] = v;
        }
      }
      // ---- z_pred = A @ z ----
      {
        int i = tid >> 3, s = tid & 7;
        float sum = 0.f;
        for (int kk = 0; kk < 16; ++kk) {
          int k = s * 16 + kk;
          sum += A[i * SD + k] * lds[OFF_Z + k];
        }
        sum += __shfl_xor(sum, 1);
        sum += __shfl_xor(sum, 2);
        sum += __shfl_xor(sum, 4);
        if (s == 0) lds[OFF_T1 + i] = sum;
      }
      if (tid == 0) lds[OFF_MISC + 2] = 1.f;
      __syncthreads();
    } else {
      if (tid < SD) lds[OFF_T1 + tid] = lds[OFF_Z + tid];
      if (tid == 0) lds[OFF_MISC + 2] = 1.f;
      __syncthreads();
    }

    // ---- PCtT = C @ P_pred  [64][128] into OFF_T rows 0..63; NaN check ----
    {
      const int a0 = ti * 2, i0 = tj * 4;
      float acc[2][4] = {};
      for (int m = 0; m < SD; m += 4) {
        float c_[2][4], p_[4][4];
#pragma unroll
        for (int r = 0; r < 2; ++r) {
          float4 v = *(const float4*)&C[(a0 + r) * SD + m];
          c_[r][0] = v.x; c_[r][1] = v.y; c_[r][2] = v.z; c_[r][3] = v.w;
        }
#pragma unroll
        for (int mm = 0; mm < 4; ++mm) {
          float4 v = *(const float4*)&lds[OFF_P + (m + mm) * PST + i0];
          p_[mm][0] = v.x; p_[mm][1] = v.y; p_[mm][2] = v.z; p_[mm][3] = v.w;
        }
#pragma unroll
        for (int r = 0; r < 2; ++r)
#pragma unroll
          for (int c = 0; c < 4; ++c)
#pragma unroll
            for (int mm = 0; mm < 4; ++mm) acc[r][c] += c_[r][mm] * p_[mm][c];
      }
#pragma unroll
      for (int r = 0; r < 2; ++r) {
        float4 v = {acc[r][0], acc[r][1], acc[r][2], acc[r][3]};
        *(float4*)&lds[OFF_T + (a0 + r) * PST + i0] = v;
      }
      if (tid < OD) {
        float yv = y[(size_t)t * OD + tid];
        if (yv != yv) lds[OFF_MISC + 2] = 0.f;
      }
    }
    __syncthreads();

    // ---- S = C P_pred C^T + R + jit = PCtT[a][:] . C[b][:] ----
    {
      const int a0 = ti * 2;
      float acc[2][2] = {};
      for (int k = 0; k < SD; k += 4) {
        float pa_[2][4], cb_[2][4];
#pragma unroll
        for (int r = 0; r < 2; ++r) {
          float4 v = *(const float4*)&lds[OFF_T + (a0 + r) * PST + k];
          pa_[r][0] = v.x; pa_[r][1] = v.y; pa_[r][2] = v.z; pa_[r][3] = v.w;
        }
#pragma unroll
        for (int cb = 0; cb < 2; ++cb) {
          float4 v = *(const float4*)&C[(tj + 32 * cb) * SD + k];
          cb_[cb][0] = v.x; cb_[cb][1] = v.y; cb_[cb][2] = v.z; cb_[cb][3] = v.w;
        }
#pragma unroll
        for (int r = 0; r < 2; ++r)
#pragma unroll
          for (int cb = 0; cb < 2; ++cb)
#pragma unroll
            for (int kk = 0; kk < 4; ++kk) acc[r][cb] += pa_[r][kk] * cb_[cb][kk];
      }
#pragma unroll
      for (int r = 0; r < 2; ++r)
#pragma unroll
        for (int cb = 0; cb < 2; ++cb) {
          int a = a0 + r, b = tj + 32 * cb;
          lds[OFF_S + a * SST + b] =
              acc[r][cb] + R[a * OD + b] + ((a == b) ? 1e-6f : 0.f);
        }
    }
    // ---- innov = y_safe - C z_pred ----
    if (tid < 512) {
      int o = tid >> 3, s = tid & 7;
      float sum = 0.f;
      for (int kk = 0; kk < 16; ++kk) {
        int k = s * 16 + kk;
        sum += C[o * SD + k] * lds[OFF_T1 + k];
      }
      sum += __shfl_xor(sum, 1);
      sum += __shfl_xor(sum, 2);
      sum += __shfl_xor(sum, 4);
      if (s == 0) {
        float yv = y[(size_t)t * OD + o];
        if (yv != yv) yv = 0.f;
        lds[OFF_INNOV + o] = yv - sum;
      }
    }
    __syncthreads();

    // ---- register Cholesky (wave 0): lane i holds row i of S; fully unrolled,
    //      shfl broadcasts, no LDS in the inner loop. L written back to OFF_S. ----
    logdet_step = 0.f;
    if (tid < 64) {
      const int i = tid;
      float r[64];
#pragma unroll
      for (int k = 0; k < 64; ++k) r[k] = lds[OFF_S + i * SST + k];
      float logd = 0.f;
#pragma unroll
      for (int j = 0; j < 64; ++j) {
        float p = __shfl(r[j], j);          // pivot S~[j][j] (lane j is valid)
        float irs = rsqrtf(p);
        logd += logf(p);                    // uniform; lane 0's copy is used
        float lij = r[j] * irs;             // L[i][j] for i>=j (others dead)
#pragma unroll
        for (int k = j + 1; k < 64; ++k) {
          float lkj = __shfl(lij, k);       // L[k][j] from lane k (k>j valid)
          r[k] -= lij * lkj;                // trailing update (dead for i<=j)
        }
        r[j] = lij;
      }
#pragma unroll
      for (int k = 0; k < 64; ++k) lds[OFF_S + i * SST + k] = r[k];
      logdet_step = logd;
    }
    __syncthreads();

    // ---- solve S X = [PCtT | innov] with x in registers (static indices);
    //      L reads are wave-uniform broadcasts. Results -> OFF_T rows 64..127. ----
    if (tid < 129) {
      const int c = tid;
      float x[64];
#pragma unroll
      for (int i = 0; i < 64; ++i)
        x[i] = (c < SD) ? lds[OFF_T + i * PST + c] : lds[OFF_INNOV + i];
#pragma unroll
      for (int i = 0; i < 64; ++i) {
        float s0 = x[i], s1 = 0.f;
#pragma unroll
        for (int j = 0; j + 1 < i; j += 2) {
          s0 -= lds[OFF_S + i * SST + j]     * x[j];
          s1 -= lds[OFF_S + i * SST + j + 1] * x[j + 1];
        }
        if (i & 1) s0 -= lds[OFF_S + i * SST + (i - 1)] * x[i - 1];
        x[i] = (s0 + s1) / lds[OFF_S + i * SST + i];
      }
#pragma unroll
      for (int i = 63; i >= 0; --i) {
        float s0 = x[i], s1 = 0.f;
#pragma unroll
        for (int j = i + 1; j + 1 < 64; j += 2) {
          s0 -= lds[OFF_S + j * SST + i]       * x[j];
          s1 -= lds[OFF_S + (j + 1) * SST + i] * x[j + 1];
        }
        if ((64 - i - 1) & 1) s0 -= lds[OFF_S + 63 * SST + i] * x[63];
        x[i] = (s0 + s1) / lds[OFF_S + i * SST + i];
      }
#pragma unroll
      for (int i = 0; i < 64; ++i) lds[OFF_T + (64 + i) * PST + c] = x[i];
    }
    __syncthreads();

    const bool valid = (lds[OFF_MISC + 2] != 0.f);
    // ---- quad + ll (wave 0) ----
    if (tid < 64) {
      float q = lds[OFF_INNOV + tid] * lds[OFF_T + (64 + tid) * PST + 128];
      q += __shfl_xor(q, 1);  q += __shfl_xor(q, 2);  q += __shfl_xor(q, 4);
      q += __shfl_xor(q, 8);  q += __shfl_xor(q, 16); q += __shfl_xor(q, 32);
      if (tid == 0) {
        logdet_cur = logdet_step;
        if (valid) llacc += -0.5f * (logdet_step + q + OD * LOG2PI_F);
      }
    }
    // ---- z update ----
    {
      int i = tid >> 3, s = tid & 7;
      float sum = 0.f;
      for (int kk = 0; kk < 8; ++kk) {
        int k = s * 8 + kk;
        sum += lds[OFF_T + (64 + k) * PST + i] * lds[OFF_INNOV + k];
      }
      sum += __shfl_xor(sum, 1);
      sum += __shfl_xor(sum, 2);
      sum += __shfl_xor(sum, 4);
      if (s == 0) {
        float zi = lds[OFF_T1 + i] + (valid ? sum : 0.f);
        lds[OFF_Z + i] = zi;
        states[(size_t)t * SD + i] = zi;
      }
    }
    // ---- P_u = P_pred - KT^T @ PCtT ----
    {
      const int i0 = ti * 4, j0 = tj * 4;
      float acc[4][4] = {};
      for (int a = 0; a < OD; ++a) {
        float4 kt4 = *(const float4*)&lds[OFF_T + (64 + a) * PST + i0];  // broadcast
        float4 pc4 = *(const float4*)&lds[OFF_T + a * PST + j0];
        float kt_[4] = {kt4.x, kt4.y, kt4.z, kt4.w};
        float pc_[4] = {pc4.x, pc4.y, pc4.z, pc4.w};
#pragma unroll
        for (int r = 0; r < 4; ++r)
#pragma unroll
          for (int c = 0; c < 4; ++c) acc[r][c] += kt_[r] * pc_[c];
      }
      if (valid) {
#pragma unroll
        for (int r = 0; r < 4; ++r) {
          float4 v = *(const float4*)&lds[OFF_P + (i0 + r) * PST + j0];
          v.x -= acc[r][0]; v.y -= acc[r][1]; v.z -= acc[r][2]; v.w -= acc[r][3];
          *(float4*)&lds[OFF_P + (i0 + r) * PST + j0] = v;
        }
      }
    }
    __syncthreads();

    // ---- write cov[t], convergence check ----
    {
      float maxd = 0.f;
      float* covt = cov + (size_t)t * SD * SD;
      const float4* covp = (const float4*)(cov + (size_t)(t - 1) * SD * SD);
#pragma unroll
      for (int p = 0; p < 4; ++p) {
        int idx = tid + p * NTH;               // 4096 float4s
        int i = idx >> 5, j = (idx & 31) * 4;
        float4 v = *(const float4*)&lds[OFF_P + i * PST + j];
        ((float4*)covt)[idx] = v;
        if (t > 0 && !hasNaN) {
          float4 pv = covp[idx];
          maxd = fmaxf(maxd, fmaxf(fmaxf(fabsf(v.x - pv.x), fabsf(v.y - pv.y)),
                                   fmaxf(fabsf(v.z - pv.z), fabsf(v.w - pv.w))));
        }
      }
      for (int m = 1; m < 64; m <<= 1) maxd = fmaxf(maxd, __shfl_xor(maxd, m));
      if ((tid & 63) == 0) lds[OFF_RED + (tid >> 6)] = maxd;
    }
    __syncthreads();
    if (tid == 0) {
      float md = 0.f;
      for (int w = 0; w < 16; ++w) md = fmaxf(md, lds[OFF_RED + w]);
      if (t > 0 && !hasNaN && md < FREEZE_TOL) lds[OFF_MISC + 0] = 1.f;
    }
    __syncthreads();
    if (lds[OFF_MISC + 0] != 0.f) { tF = t + 1; break; }
    __syncthreads();
  }

  // ---- export steady-state data ----
  if (tid == 0) {
    wsi[0] = tF;
    wsf[WS_LL] = llacc;
    wsf[WS_LOGD] = logdet_cur;
  }
  if (tid < SD) wsf[WS_Z + tid] = lds[OFF_Z + tid];
  if (tF < T) {
    // KT -> ws (before Sinv solve reuses the region)
    for (int p = 0; p < 8; ++p) {
      int idx = tid + p * NTH;
      int a = idx >> 7, i2 = idx & 127;
      wsf[WS_KT + idx] = lds[OFF_T + (64 + a) * PST + i2];
    }
    __syncthreads();
    // Sinv = solve(S, I) per column (threads 0..63)
    if (tid < 64) {
      const int c = tid;
      const int xb = OFF_T + 64 * PST + c;
      for (int i = 0; i < OD; ++i) {
        float s0 = (i == c) ? 1.f : 0.f;
        for (int j = 0; j < i; ++j)
          s0 -= lds[OFF_S + i * SST + j] * lds[xb + j * PST];
        lds[xb + i * PST] = s0 / lds[OFF_S + i * SST + i];
      }
      for (int i = OD - 1; i >= 0; --i) {
        float s0 = lds[xb + i * PST];
        for (int j = i + 1; j < OD; ++j)
          s0 -= lds[OFF_S + j * SST + i] * lds[xb + j * PST];
        float xi = s0 / lds[OFF_S + i * SST + i];
        lds[xb + i * PST] = xi;
        wsf[WS_SINV + i * OD + c] = xi;
      }
    }
    __syncthreads();
    // stage A, compute CA = C @ A
    for (int p = 0; p < 16; ++p) {
      int idx = tid + p * NTH;
      lds[OFF_P + (idx >> 7) * PST + (idx & 127)] = A[idx];
    }
    __syncthreads();
    {
      const int a0 = ti * 2, k0 = tj * 4;
      float acc[2][4] = {};
      for (int m = 0; m < SD; m += 4) {
        float c_[2][4], a_[4][4];
#pragma unroll
        for (int r = 0; r < 2; ++r) {
          float4 v = *(const float4*)&C[(a0 + r) * SD + m];
          c_[r][0] = v.x; c_[r][1] = v.y; c_[r][2] = v.z; c_[r][3] = v.w;
        }
#pragma unroll
        for (int mm = 0; mm < 4; ++mm) {
          float4 v = *(const float4*)&lds[OFF_P + (m + mm) * PST + k0];
          a_[mm][0] = v.x; a_[mm][1] = v.y; a_[mm][2] = v.z; a_[mm][3] = v.w;
        }
#pragma unroll
        for (int r = 0; r < 2; ++r)
#pragma unroll
          for (int cc = 0; cc < 4; ++cc)
#pragma unroll
            for (int mm = 0; mm < 4; ++mm) acc[r][cc] += c_[r][mm] * a_[mm][cc];
      }
#pragma unroll
      for (int r = 0; r < 2; ++r)
#pragma unroll
        for (int cc = 0; cc < 4; ++cc)
          wsf[WS_CA + (a0 + r) * SD + k0 + cc] = acc[r][cc];
    }
  }
}

// Parallel frozen-phase recursion (unchanged)
__launch_bounds__(512, 1)
__global__ void kf_chunk(const float* __restrict__ y, const float* __restrict__ A,
                         const float* __restrict__ wsf, const int* __restrict__ wsi,
                         float* __restrict__ out, int T) {
  __shared__ __align__(16) float zv[SD];
  __shared__ __align__(16) float vv[192];
  __shared__ __align__(16) float yb[2][OD];
  __shared__ float red[8];
  const int tid = (int)threadIdx.x;
  const int c = (int)blockIdx.x;
  const int tF = wsi[0];
  float* states = out;
  float* quad_out = (float*)wsf + WS_QUAD;

  int t_end = (c + 1) * LCH; if (t_end > T) t_end = T;
  int t_begin = c * LCH; if (t_begin < tF) t_begin = tF;
  float qacc = 0.f;

  if (t_begin < t_end) {
    int s0 = t_begin - WARM; if (s0 < tF) s0 = tF;
    const int r = tid >> 1, h = tid & 1;
    const int ki = tid >> 2, kq = tid & 3;
    const int so = tid >> 3, se = tid & 7;

    float G[64];
    if (tid < 384) {
      const float* src = (r < SD) ? (A + r * SD + h * 64)
                                  : (wsf + WS_CA + (r - SD) * SD + h * 64);
#pragma unroll
      for (int k = 0; k < 16; ++k) {
        float4 g4 = ((const float4*)src)[k];
        G[4 * k + 0] = g4.x; G[4 * k + 1] = g4.y;
        G[4 * k + 2] = g4.z; G[4 * k + 3] = g4.w;
      }
    }
    float K[16];
#pragma unroll
    for (int k = 0; k < 16; ++k) K[k] = wsf[WS_KT + (kq * 16 + k) * SD + ki];
    float Sv[8];
#pragma unroll
    for (int k = 0; k < 8; ++k) Sv[k] = wsf[WS_SINV + so * OD + se * 8 + k];

    if (tid < SD) zv[tid] = (s0 == tF) ? wsf[WS_Z + tid] : 0.f;
    if (tid < OD) yb[s0 & 1][tid] = y[(size_t)s0 * OD + tid];
    __syncthreads();

    for (int t = s0; t < t_end; ++t) {
      if (tid < 384) {
        const float* zz = zv + h * 64;
        float sum = 0.f;
#pragma unroll
        for (int k = 0; k < 16; ++k) {
          float4 z4 = ((const float4*)zz)[k];
          sum += G[4 * k + 0] * z4.x + G[4 * k + 1] * z4.y +
                 G[4 * k + 2] * z4.z + G[4 * k + 3] * z4.w;
        }
        sum += __shfl_xor(sum, 1);
        if (h == 0) vv[r] = sum;
      } else if (tid >= 448) {
        int o = tid - 448;
        if (t + 1 < t_end) yb[(t + 1) & 1][o] = y[(size_t)(t + 1) * OD + o];
      }
      __syncthreads();
      const float* ybt = yb[t & 1];
      {
        const int a0 = kq * 16;
        float sum = 0.f;
#pragma unroll
        for (int k4 = 0; k4 < 4; ++k4) {
          float4 y4 = ((const float4*)(ybt + a0))[k4];
          float4 v4 = ((const float4*)(vv + SD + a0))[k4];
          sum += K[4 * k4 + 0] * (y4.x - v4.x) + K[4 * k4 + 1] * (y4.y - v4.y) +
                 K[4 * k4 + 2] * (y4.z - v4.z) + K[4 * k4 + 3] * (y4.w - v4.w);
        }
        sum += __shfl_xor(sum, 1);
        sum += __shfl_xor(sum, 2);
        if (kq == 0) {
          float zi = vv[ki] + sum;
          zv[ki] = zi;
          if (t >= t_begin) states[(size_t)t * SD + ki] = zi;
        }
      }
      if (t >= t_begin) {
        const int b0 = se * 8;
        float sp = 0.f;
#pragma unroll
        for (int k4 = 0; k4 < 2; ++k4) {
          float4 y4 = ((const float4*)(ybt + b0))[k4];
          float4 v4 = ((const float4*)(vv + SD + b0))[k4];
          sp += Sv[4 * k4 + 0] * (y4.x - v4.x) + Sv[4 * k4 + 1] * (y4.y - v4.y) +
                Sv[4 * k4 + 2] * (y4.z - v4.z) + Sv[4 * k4 + 3] * (y4.w - v4.w);
        }
        qacc += sp * (ybt[so] - vv[SD + so]);
      }
      __syncthreads();
    }
  }

  float q = qacc;
  for (int m = 1; m < 64; m <<= 1) q += __shfl_xor(q, m);
  if ((tid & 63) == 0) red[tid >> 6] = q;
  __syncthreads();
  if (tid == 0) {
    float s = 0.f;
    for (int w = 0; w < 8; ++w) s += red[w];
    quad_out[c] = s;
  }
}

__global__ void kf_ll(const float* __restrict__ wsf, const int* __restrict__ wsi,
                      float* __restrict__ out, int T, int nchunks) {
  if (threadIdx.x == 0 && blockIdx.x == 0) {
    int tF = wsi[0];
    float ll = wsf[WS_LL];
    if (tF < T) {
      float qs = 0.f;
      for (int c = 0; c < nchunks; ++c) qs += wsf[WS_QUAD + c];
      ll += -0.5f * (qs + (float)(T - tF) * (wsf[WS_LOGD] + (float)OD * LOG2PI_F));
    }
    out[(size_t)T * SD + (size_t)T * SD * SD] = ll;
  }
}

__global__ void kf_fill(float* __restrict__ cov, const int* __restrict__ ws_tf, int T) {
  int t = (int)blockIdx.x;
  int tF = ws_tf[0];
  if (t < tF) return;
  const float4* src = (const float4*)(cov + (size_t)(tF - 1) * SD * SD);
  float4* dst = (float4*)(cov + (size_t)t * SD * SD);
#pragma unroll
  for (int p = 0; p < 16; ++p) {
    int idx = (int)threadIdx.x + p * 256;
    dst[idx] = src[idx];
  }
}

extern "C" void kernel_launch(void* const* d_in, const int* in_sizes, int n_in,
                              void* d_out, int out_size, void* d_ws, size_t ws_size,
                              hipStream_t stream) {
  const float* y  = (const float*)d_in[0];
  const float* A  = (const float*)d_in[1];
  const float* C  = (const float*)d_in[2];
  const float* Q  = (const float*)d_in[3];
  const float* R  = (const float*)d_in[4];
  const float* z0 = (const float*)d_in[5];
  const float* P0 = (const float*)d_in[6];
  float* out = (float*)d_out;
  int T = in_sizes[0] / OD;
  float* wsf = (float*)d_ws;
  int* wsi = (int*)d_ws;

  size_t ldsBytes = (size_t)LDS_FLOATS * sizeof(float);
  (void)hipFuncSetAttribute((const void*)kf_seq,
                            hipFuncAttributeMaxDynamicSharedMemorySize,
                            (int)ldsBytes);

  kf_seq<<<dim3(1), dim3(NTH), ldsBytes, stream>>>(y, A, C, Q, R, z0, P0, out, T, wsf, wsi);

  int nch = (T + LCH - 1) / LCH;
  kf_chunk<<<dim3(nch), dim3(512), 0, stream>>>(y, A, wsf, wsi, out, T);
  kf_ll<<<dim3(1), dim3(64), 0, stream>>>(wsf, wsi, out, T, nch);

  float* cov = out + (size_t)T * SD;
  kf_fill<<<dim3(T), dim3(256), 0, stream>>>(cov, wsi, T);
}

// Round 6
// 4230.951 us; speedup vs baseline: 1.1930x; 1.0029x over previous
//
#include <hip/hip_runtime.h>
#include <math.h>

#define NTH 1024
#define SD 128
#define OD 64
#define PST 132   // row stride (floats) for 128-wide LDS matrices (16B-aligned rows)
#define SST 65    // row stride for 64x64 S/L

// LDS float offsets (kf_seq)
#define OFF_P     0                    // [128][132] P / P_pred ; export: A staging
#define OFF_T     16896                // [128][132]: X temp; then PCtT rows 0..63, KT+qcol rows 64..127
#define OFF_S     33792                // [64][65]  S lower -> L in place
#define OFF_Z     37952                // 128
#define OFF_T1    38080                // 128 (z_pred)
#define OFF_INNOV 38208                // 64
#define OFF_RED   38272                // 64
#define OFF_MISC  38336                // [0]=frozen [1]=hasNaN [2]=valid
#define LDS_FLOATS 38344               // 153.4 KB

// ws float offsets
#define WS_LL    1
#define WS_LOGD  2
#define WS_Z     128
#define WS_KT    1024        // [64][128]  KT[a][i] = K[i][a]
#define WS_SINV  10240       // [64][64]
#define WS_CA    16384       // [64][128]
#define WS_QUAD  24576       // [64] chunk partial quad sums

#define LCH  32
#define WARM 160

#define LOG2PI_F 1.8378770664093453f
#define FREEZE_TOL 1e-4f

// min-waves/EU = 1: relax VGPR budget to 128 (16-wave workgroup cap) so the
// register-resident Cholesky r[64] and trsm x[64] do NOT spill to scratch.
// Round-5 evidence: default heuristic capped at 64 VGPR -> ~16 MB/dispatch
// spill traffic (FETCH 6.4 MB, WRITE 14.3 MB).
__launch_bounds__(NTH, 1)
__global__ void kf_seq(const float* __restrict__ y, const float* __restrict__ A,
                       const float* __restrict__ C, const float* __restrict__ Q,
                       const float* __restrict__ R, const float* __restrict__ z0,
                       const float* __restrict__ P0, float* __restrict__ out,
                       int T, float* __restrict__ wsf, int* __restrict__ wsi) {
  extern __shared__ float lds[];
  const int tid = (int)threadIdx.x;
  const int ti = tid >> 5, tj = tid & 31;
  float* states = out;
  float* cov = out + (size_t)T * SD;

  // ---- init: P <- P0, z <- z0 ----
  for (int p = 0; p < 16; ++p) {
    int idx = tid + p * NTH;
    lds[OFF_P + (idx >> 7) * PST + (idx & 127)] = P0[idx];
  }
  if (tid < SD) lds[OFF_Z + tid] = z0[tid];
  if (tid == 0) { lds[OFF_MISC + 0] = 0.f; lds[OFF_MISC + 1] = 0.f; }
  __syncthreads();

  // ---- global NaN scan of y ----
  {
    int bad = 0;
    int n4 = (T * OD) >> 2;
    for (int idx = tid; idx < n4; idx += NTH) {
      float4 v = ((const float4*)y)[idx];
      if (v.x != v.x || v.y != v.y || v.z != v.z || v.w != v.w) bad = 1;
    }
    if (bad) lds[OFF_MISC + 1] = 1.f;
  }
  __syncthreads();
  const bool hasNaN = (lds[OFF_MISC + 1] != 0.f);

  float llacc = 0.f;      // thread 0
  float logdet_cur = 0.f; // thread 0
  float logdet_step = 0.f;
  int tF = T;

  for (int t = 0; t < T; ++t) {
    if (t > 0) {
      // ---- X = A @ P  (tile i0..i0+3, j0..j0+3) ----
      {
        const int i0 = ti * 4, j0 = tj * 4;
        float acc[4][4] = {};
        for (int k = 0; k < SD; k += 4) {
          float a_[4][4], p_[4][4];
#pragma unroll
          for (int r = 0; r < 4; ++r) {
            float4 v = *(const float4*)&A[(i0 + r) * SD + k];
            a_[r][0] = v.x; a_[r][1] = v.y; a_[r][2] = v.z; a_[r][3] = v.w;
          }
#pragma unroll
          for (int kk = 0; kk < 4; ++kk) {
            float4 v = *(const float4*)&lds[OFF_P + (k + kk) * PST + j0];
            p_[kk][0] = v.x; p_[kk][1] = v.y; p_[kk][2] = v.z; p_[kk][3] = v.w;
          }
#pragma unroll
          for (int r = 0; r < 4; ++r)
#pragma unroll
            for (int c = 0; c < 4; ++c)
#pragma unroll
              for (int kk = 0; kk < 4; ++kk) acc[r][c] += a_[r][kk] * p_[kk][c];
        }
#pragma unroll
        for (int r = 0; r < 4; ++r) {
          float4 v = {acc[r][0], acc[r][1], acc[r][2], acc[r][3]};
          *(float4*)&lds[OFF_T + (i0 + r) * PST + j0] = v;
        }
      }
      __syncthreads();
      // ---- P_pred = X @ A^T + Q  (symmetry of A P A^T); X-row reads broadcast ----
      {
        const int i0 = ti * 4, j0 = tj * 4;
        float acc[4][4] = {};
        for (int k = 0; k < SD; k += 4) {
          float x_[4][4], a_[4][4];
#pragma unroll
          for (int r = 0; r < 4; ++r) {
            float4 v = *(const float4*)&lds[OFF_T + (i0 + r) * PST + k];
            x_[r][0] = v.x; x_[r][1] = v.y; x_[r][2] = v.z; x_[r][3] = v.w;
          }
#pragma unroll
          for (int c = 0; c < 4; ++c) {
            float4 v = *(const float4*)&A[(j0 + c) * SD + k];
            a_[c][0] = v.x; a_[c][1] = v.y; a_[c][2] = v.z; a_[c][3] = v.w;
          }
#pragma unroll
          for (int r = 0; r < 4; ++r)
#pragma unroll
            for (int c = 0; c < 4; ++c)
#pragma unroll
              for (int kk = 0; kk < 4; ++kk) acc[r][c] += x_[r][kk] * a_[c][kk];
        }
#pragma unroll
        for (int r = 0; r < 4; ++r) {
          float4 q4 = *(const float4*)&Q[(i0 + r) * SD + j0];
          float4 v = {acc[r][0] + q4.x, acc[r][1] + q4.y,
                      acc[r][2] + q4.z, acc[r][3] + q4.w};
          *(float4*)&lds[OFF_P + (i0 + r) * PST + j0] = v;
        }
      }
      // ---- z_pred = A @ z ----
      {
        int i = tid >> 3, s = tid & 7;
        float sum = 0.f;
        for (int kk = 0; kk < 16; ++kk) {
          int k = s * 16 + kk;
          sum += A[i * SD + k] * lds[OFF_Z + k];
        }
        sum += __shfl_xor(sum, 1);
        sum += __shfl_xor(sum, 2);
        sum += __shfl_xor(sum, 4);
        if (s == 0) lds[OFF_T1 + i] = sum;
      }
      if (tid == 0) lds[OFF_MISC + 2] = 1.f;
      __syncthreads();
    } else {
      if (tid < SD) lds[OFF_T1 + tid] = lds[OFF_Z + tid];
      if (tid == 0) lds[OFF_MISC + 2] = 1.f;
      __syncthreads();
    }

    // ---- PCtT = C @ P_pred  [64][128] into OFF_T rows 0..63; NaN check ----
    {
      const int a0 = ti * 2, i0 = tj * 4;
      float acc[2][4] = {};
      for (int m = 0; m < SD; m += 4) {
        float c_[2][4], p_[4][4];
#pragma unroll
        for (int r = 0; r < 2; ++r) {
          float4 v = *(const float4*)&C[(a0 + r) * SD + m];
          c_[r][0] = v.x; c_[r][1] = v.y; c_[r][2] = v.z; c_[r][3] = v.w;
        }
#pragma unroll
        for (int mm = 0; mm < 4; ++mm) {
          float4 v = *(const float4*)&lds[OFF_P + (m + mm) * PST + i0];
          p_[mm][0] = v.x; p_[mm][1] = v.y; p_[mm][2] = v.z; p_[mm][3] = v.w;
        }
#pragma unroll
        for (int r = 0; r < 2; ++r)
#pragma unroll
          for (int c = 0; c < 4; ++c)
#pragma unroll
            for (int mm = 0; mm < 4; ++mm) acc[r][c] += c_[r][mm] * p_[mm][c];
      }
#pragma unroll
      for (int r = 0; r < 2; ++r) {
        float4 v = {acc[r][0], acc[r][1], acc[r][2], acc[r][3]};
        *(float4*)&lds[OFF_T + (a0 + r) * PST + i0] = v;
      }
      if (tid < OD) {
        float yv = y[(size_t)t * OD + tid];
        if (yv != yv) lds[OFF_MISC + 2] = 0.f;
      }
    }
    __syncthreads();

    // ---- S = C P_pred C^T + R + jit = PCtT[a][:] . C[b][:] ----
    {
      const int a0 = ti * 2;
      float acc[2][2] = {};
      for (int k = 0; k < SD; k += 4) {
        float pa_[2][4], cb_[2][4];
#pragma unroll
        for (int r = 0; r < 2; ++r) {
          float4 v = *(const float4*)&lds[OFF_T + (a0 + r) * PST + k];
          pa_[r][0] = v.x; pa_[r][1] = v.y; pa_[r][2] = v.z; pa_[r][3] = v.w;
        }
#pragma unroll
        for (int cb = 0; cb < 2; ++cb) {
          float4 v = *(const float4*)&C[(tj + 32 * cb) * SD + k];
          cb_[cb][0] = v.x; cb_[cb][1] = v.y; cb_[cb][2] = v.z; cb_[cb][3] = v.w;
        }
#pragma unroll
        for (int r = 0; r < 2; ++r)
#pragma unroll
          for (int cb = 0; cb < 2; ++cb)
#pragma unroll
            for (int kk = 0; kk < 4; ++kk) acc[r][cb] += pa_[r][kk] * cb_[cb][kk];
      }
#pragma unroll
      for (int r = 0; r < 2; ++r)
#pragma unroll
        for (int cb = 0; cb < 2; ++cb) {
          int a = a0 + r, b = tj + 32 * cb;
          lds[OFF_S + a * SST + b] =
              acc[r][cb] + R[a * OD + b] + ((a == b) ? 1e-6f : 0.f);
        }
    }
    // ---- innov = y_safe - C z_pred ----
    if (tid < 512) {
      int o = tid >> 3, s = tid & 7;
      float sum = 0.f;
      for (int kk = 0; kk < 16; ++kk) {
        int k = s * 16 + kk;
        sum += C[o * SD + k] * lds[OFF_T1 + k];
      }
      sum += __shfl_xor(sum, 1);
      sum += __shfl_xor(sum, 2);
      sum += __shfl_xor(sum, 4);
      if (s == 0) {
        float yv = y[(size_t)t * OD + o];
        if (yv != yv) yv = 0.f;
        lds[OFF_INNOV + o] = yv - sum;
      }
    }
    __syncthreads();

    // ---- register Cholesky (wave 0): lane i holds row i of S; fully unrolled,
    //      shfl broadcasts, no LDS in the inner loop. L written back to OFF_S. ----
    logdet_step = 0.f;
    if (tid < 64) {
      const int i = tid;
      float r[64];
#pragma unroll
      for (int k = 0; k < 64; ++k) r[k] = lds[OFF_S + i * SST + k];
      float logd = 0.f;
#pragma unroll
      for (int j = 0; j < 64; ++j) {
        float p = __shfl(r[j], j);          // pivot S~[j][j] (lane j is valid)
        float irs = rsqrtf(p);
        logd += logf(p);                    // uniform; lane 0's copy is used
        float lij = r[j] * irs;             // L[i][j] for i>=j (others dead)
#pragma unroll
        for (int k = j + 1; k < 64; ++k) {
          float lkj = __shfl(lij, k);       // L[k][j] from lane k (k>j valid)
          r[k] -= lij * lkj;                // trailing update (dead for i<=j)
        }
        r[j] = lij;
      }
#pragma unroll
      for (int k = 0; k < 64; ++k) lds[OFF_S + i * SST + k] = r[k];
      logdet_step = logd;
    }
    __syncthreads();

    // ---- solve S X = [PCtT | innov] with x in registers (static indices);
    //      L reads are wave-uniform broadcasts. Results -> OFF_T rows 64..127. ----
    if (tid < 129) {
      const int c = tid;
      float x[64];
#pragma unroll
      for (int i = 0; i < 64; ++i)
        x[i] = (c < SD) ? lds[OFF_T + i * PST + c] : lds[OFF_INNOV + i];
#pragma unroll
      for (int i = 0; i < 64; ++i) {
        float s0 = x[i], s1 = 0.f;
#pragma unroll
        for (int j = 0; j + 1 < i; j += 2) {
          s0 -= lds[OFF_S + i * SST + j]     * x[j];
          s1 -= lds[OFF_S + i * SST + j + 1] * x[j + 1];
        }
        if (i & 1) s0 -= lds[OFF_S + i * SST + (i - 1)] * x[i - 1];
        x[i] = (s0 + s1) / lds[OFF_S + i * SST + i];
      }
#pragma unroll
      for (int i = 63; i >= 0; --i) {
        float s0 = x[i], s1 = 0.f;
#pragma unroll
        for (int j = i + 1; j + 1 < 64; j += 2) {
          s0 -= lds[OFF_S + j * SST + i]       * x[j];
          s1 -= lds[OFF_S + (j + 1) * SST + i] * x[j + 1];
        }
        if ((64 - i - 1) & 1) s0 -= lds[OFF_S + 63 * SST + i] * x[63];
        x[i] = (s0 + s1) / lds[OFF_S + i * SST + i];
      }
#pragma unroll
      for (int i = 0; i < 64; ++i) lds[OFF_T + (64 + i) * PST + c] = x[i];
    }
    __syncthreads();

    const bool valid = (lds[OFF_MISC + 2] != 0.f);
    // ---- quad + ll (wave 0) ----
    if (tid < 64) {
      float q = lds[OFF_INNOV + tid] * lds[OFF_T + (64 + tid) * PST + 128];
      q += __shfl_xor(q, 1);  q += __shfl_xor(q, 2);  q += __shfl_xor(q, 4);
      q += __shfl_xor(q, 8);  q += __shfl_xor(q, 16); q += __shfl_xor(q, 32);
      if (tid == 0) {
        logdet_cur = logdet_step;
        if (valid) llacc += -0.5f * (logdet_step + q + OD * LOG2PI_F);
      }
    }
    // ---- z update ----
    {
      int i = tid >> 3, s = tid & 7;
      float sum = 0.f;
      for (int kk = 0; kk < 8; ++kk) {
        int k = s * 8 + kk;
        sum += lds[OFF_T + (64 + k) * PST + i] * lds[OFF_INNOV + k];
      }
      sum += __shfl_xor(sum, 1);
      sum += __shfl_xor(sum, 2);
      sum += __shfl_xor(sum, 4);
      if (s == 0) {
        float zi = lds[OFF_T1 + i] + (valid ? sum : 0.f);
        lds[OFF_Z + i] = zi;
        states[(size_t)t * SD + i] = zi;
      }
    }
    // ---- P_u = P_pred - KT^T @ PCtT ----
    {
      const int i0 = ti * 4, j0 = tj * 4;
      float acc[4][4] = {};
      for (int a = 0; a < OD; ++a) {
        float4 kt4 = *(const float4*)&lds[OFF_T + (64 + a) * PST + i0];  // broadcast
        float4 pc4 = *(const float4*)&lds[OFF_T + a * PST + j0];
        float kt_[4] = {kt4.x, kt4.y, kt4.z, kt4.w};
        float pc_[4] = {pc4.x, pc4.y, pc4.z, pc4.w};
#pragma unroll
        for (int r = 0; r < 4; ++r)
#pragma unroll
          for (int c = 0; c < 4; ++c) acc[r][c] += kt_[r] * pc_[c];
      }
      if (valid) {
#pragma unroll
        for (int r = 0; r < 4; ++r) {
          float4 v = *(const float4*)&lds[OFF_P + (i0 + r) * PST + j0];
          v.x -= acc[r][0]; v.y -= acc[r][1]; v.z -= acc[r][2]; v.w -= acc[r][3];
          *(float4*)&lds[OFF_P + (i0 + r) * PST + j0] = v;
        }
      }
    }
    __syncthreads();

    // ---- write cov[t], convergence check ----
    {
      float maxd = 0.f;
      float* covt = cov + (size_t)t * SD * SD;
      const float4* covp = (const float4*)(cov + (size_t)(t - 1) * SD * SD);
#pragma unroll
      for (int p = 0; p < 4; ++p) {
        int idx = tid + p * NTH;               // 4096 float4s
        int i = idx >> 5, j = (idx & 31) * 4;
        float4 v = *(const float4*)&lds[OFF_P + i * PST + j];
        ((float4*)covt)[idx] = v;
        if (t > 0 && !hasNaN) {
          float4 pv = covp[idx];
          maxd = fmaxf(maxd, fmaxf(fmaxf(fabsf(v.x - pv.x), fabsf(v.y - pv.y)),
                                   fmaxf(fabsf(v.z - pv.z), fabsf(v.w - pv.w))));
        }
      }
      for (int m = 1; m < 64; m <<= 1) maxd = fmaxf(maxd, __shfl_xor(maxd, m));
      if ((tid & 63) == 0) lds[OFF_RED + (tid >> 6)] = maxd;
    }
    __syncthreads();
    if (tid == 0) {
      float md = 0.f;
      for (int w = 0; w < 16; ++w) md = fmaxf(md, lds[OFF_RED + w]);
      if (t > 0 && !hasNaN && md < FREEZE_TOL) lds[OFF_MISC + 0] = 1.f;
    }
    __syncthreads();
    if (lds[OFF_MISC + 0] != 0.f) { tF = t + 1; break; }
    __syncthreads();
  }

  // ---- export steady-state data ----
  if (tid == 0) {
    wsi[0] = tF;
    wsf[WS_LL] = llacc;
    wsf[WS_LOGD] = logdet_cur;
  }
  if (tid < SD) wsf[WS_Z + tid] = lds[OFF_Z + tid];
  if (tF < T) {
    // KT -> ws (before Sinv solve reuses the region)
    for (int p = 0; p < 8; ++p) {
      int idx = tid + p * NTH;
      int a = idx >> 7, i2 = idx & 127;
      wsf[WS_KT + idx] = lds[OFF_T + (64 + a) * PST + i2];
    }
    __syncthreads();
    // Sinv = solve(S, I) per column (threads 0..63)
    if (tid < 64) {
      const int c = tid;
      const int xb = OFF_T + 64 * PST + c;
      for (int i = 0; i < OD; ++i) {
        float s0 = (i == c) ? 1.f : 0.f;
        for (int j = 0; j < i; ++j)
          s0 -= lds[OFF_S + i * SST + j] * lds[xb + j * PST];
        lds[xb + i * PST] = s0 / lds[OFF_S + i * SST + i];
      }
      for (int i = OD - 1; i >= 0; --i) {
        float s0 = lds[xb + i * PST];
        for (int j = i + 1; j < OD; ++j)
          s0 -= lds[OFF_S + j * SST + i] * lds[xb + j * PST];
        float xi = s0 / lds[OFF_S + i * SST + i];
        lds[xb + i * PST] = xi;
        wsf[WS_SINV + i * OD + c] = xi;
      }
    }
    __syncthreads();
    // stage A, compute CA = C @ A
    for (int p = 0; p < 16; ++p) {
      int idx = tid + p * NTH;
      lds[OFF_P + (idx >> 7) * PST + (idx & 127)] = A[idx];
    }
    __syncthreads();
    {
      const int a0 = ti * 2, k0 = tj * 4;
      float acc[2][4] = {};
      for (int m = 0; m < SD; m += 4) {
        float c_[2][4], a_[4][4];
#pragma unroll
        for (int r = 0; r < 2; ++r) {
          float4 v = *(const float4*)&C[(a0 + r) * SD + m];
          c_[r][0] = v.x; c_[r][1] = v.y; c_[r][2] = v.z; c_[r][3] = v.w;
        }
#pragma unroll
        for (int mm = 0; mm < 4; ++mm) {
          float4 v = *(const float4*)&lds[OFF_P + (m + mm) * PST + k0];
          a_[mm][0] = v.x; a_[mm][1] = v.y; a_[mm][2] = v.z; a_[mm][3] = v.w;
        }
#pragma unroll
        for (int r = 0; r < 2; ++r)
#pragma unroll
          for (int cc = 0; cc < 4; ++cc)
#pragma unroll
            for (int mm = 0; mm < 4; ++mm) acc[r][cc] += c_[r][mm] * a_[mm][cc];
      }
#pragma unroll
      for (int r = 0; r < 2; ++r)
#pragma unroll
        for (int cc = 0; cc < 4; ++cc)
          wsf[WS_CA + (a0 + r) * SD + k0 + cc] = acc[r][cc];
    }
  }
}

// Parallel frozen-phase recursion (unchanged)
__launch_bounds__(512, 1)
__global__ void kf_chunk(const float* __restrict__ y, const float* __restrict__ A,
                         const float* __restrict__ wsf, const int* __restrict__ wsi,
                         float* __restrict__ out, int T) {
  __shared__ __align__(16) float zv[SD];
  __shared__ __align__(16) float vv[192];
  __shared__ __align__(16) float yb[2][OD];
  __shared__ float red[8];
  const int tid = (int)threadIdx.x;
  const int c = (int)blockIdx.x;
  const int tF = wsi[0];
  float* states = out;
  float* quad_out = (float*)wsf + WS_QUAD;

  int t_end = (c + 1) * LCH; if (t_end > T) t_end = T;
  int t_begin = c * LCH; if (t_begin < tF) t_begin = tF;
  float qacc = 0.f;

  if (t_begin < t_end) {
    int s0 = t_begin - WARM; if (s0 < tF) s0 = tF;
    const int r = tid >> 1, h = tid & 1;
    const int ki = tid >> 2, kq = tid & 3;
    const int so = tid >> 3, se = tid & 7;

    float G[64];
    if (tid < 384) {
      const float* src = (r < SD) ? (A + r * SD + h * 64)
                                  : (wsf + WS_CA + (r - SD) * SD + h * 64);
#pragma unroll
      for (int k = 0; k < 16; ++k) {
        float4 g4 = ((const float4*)src)[k];
        G[4 * k + 0] = g4.x; G[4 * k + 1] = g4.y;
        G[4 * k + 2] = g4.z; G[4 * k + 3] = g4.w;
      }
    }
    float K[16];
#pragma unroll
    for (int k = 0; k < 16; ++k) K[k] = wsf[WS_KT + (kq * 16 + k) * SD + ki];
    float Sv[8];
#pragma unroll
    for (int k = 0; k < 8; ++k) Sv[k] = wsf[WS_SINV + so * OD + se * 8 + k];

    if (tid < SD) zv[tid] = (s0 == tF) ? wsf[WS_Z + tid] : 0.f;
    if (tid < OD) yb[s0 & 1][tid] = y[(size_t)s0 * OD + tid];
    __syncthreads();

    for (int t = s0; t < t_end; ++t) {
      if (tid < 384) {
        const float* zz = zv + h * 64;
        float sum = 0.f;
#pragma unroll
        for (int k = 0; k < 16; ++k) {
          float4 z4 = ((const float4*)zz)[k];
          sum += G[4 * k + 0] * z4.x + G[4 * k + 1] * z4.y +
                 G[4 * k + 2] * z4.z + G[4 * k + 3] * z4.w;
        }
        sum += __shfl_xor(sum, 1);
        if (h == 0) vv[r] = sum;
      } else if (tid >= 448) {
        int o = tid - 448;
        if (t + 1 < t_end) yb[(t + 1) & 1][o] = y[(size_t)(t + 1) * OD + o];
      }
      __syncthreads();
      const float* ybt = yb[t & 1];
      {
        const int a0 = kq * 16;
        float sum = 0.f;
#pragma unroll
        for (int k4 = 0; k4 < 4; ++k4) {
          float4 y4 = ((const float4*)(ybt + a0))[k4];
          float4 v4 = ((const float4*)(vv + SD + a0))[k4];
          sum += K[4 * k4 + 0] * (y4.x - v4.x) + K[4 * k4 + 1] * (y4.y - v4.y) +
                 K[4 * k4 + 2] * (y4.z - v4.z) + K[4 * k4 + 3] * (y4.w - v4.w);
        }
        sum += __shfl_xor(sum, 1);
        sum += __shfl_xor(sum, 2);
        if (kq == 0) {
          float zi = vv[ki] + sum;
          zv[ki] = zi;
          if (t >= t_begin) states[(size_t)t * SD + ki] = zi;
        }
      }
      if (t >= t_begin) {
        const int b0 = se * 8;
        float sp = 0.f;
#pragma unroll
        for (int k4 = 0; k4 < 2; ++k4) {
          float4 y4 = ((const float4*)(ybt + b0))[k4];
          float4 v4 = ((const float4*)(vv + SD + b0))[k4];
          sp += Sv[4 * k4 + 0] * (y4.x - v4.x) + Sv[4 * k4 + 1] * (y4.y - v4.y) +
                Sv[4 * k4 + 2] * (y4.z - v4.z) + Sv[4 * k4 + 3] * (y4.w - v4.w);
        }
        qacc += sp * (ybt[so] - vv[SD + so]);
      }
      __syncthreads();
    }
  }

  float q = qacc;
  for (int m = 1; m < 64; m <<= 1) q += __shfl_xor(q, m);
  if ((tid & 63) == 0) red[tid >> 6] = q;
  __syncthreads();
  if (tid == 0) {
    float s = 0.f;
    for (int w = 0; w < 8; ++w) s += red[w];
    quad_out[c] = s;
  }
}

__global__ void kf_ll(const float* __restrict__ wsf, const int* __restrict__ wsi,
                      float* __restrict__ out, int T, int nchunks) {
  if (threadIdx.x == 0 && blockIdx.x == 0) {
    int tF = wsi[0];
    float ll = wsf[WS_LL];
    if (tF < T) {
      float qs = 0.f;
      for (int c = 0; c < nchunks; ++c) qs += wsf[WS_QUAD + c];
      ll += -0.5f * (qs + (float)(T - tF) * (wsf[WS_LOGD] + (float)OD * LOG2PI_F));
    }
    out[(size_t)T * SD + (size_t)T * SD * SD] = ll;
  }
}

__global__ void kf_fill(float* __restrict__ cov, const int* __restrict__ ws_tf, int T) {
  int t = (int)blockIdx.x;
  int tF = ws_tf[0];
  if (t < tF) return;
  const float4* src = (const float4*)(cov + (size_t)(tF - 1) * SD * SD);
  float4* dst = (float4*)(cov + (size_t)t * SD * SD);
#pragma unroll
  for (int p = 0; p < 16; ++p) {
    int idx = (int)threadIdx.x + p * 256;
    dst[idx] = src[idx];
  }
}

extern "C" void kernel_launch(void* const* d_in, const int* in_sizes, int n_in,
                              void* d_out, int out_size, void* d_ws, size_t ws_size,
                              hipStream_t stream) {
  const float* y  = (const float*)d_in[0];
  const float* A  = (const float*)d_in[1];
  const float* C  = (const float*)d_in[2];
  const float* Q  = (const float*)d_in[3];
  const float* R  = (const float*)d_in[4];
  const float* z0 = (const float*)d_in[5];
  const float* P0 = (const float*)d_in[6];
  float* out = (float*)d_out;
  int T = in_sizes[0] / OD;
  float* wsf = (float*)d_ws;
  int* wsi = (int*)d_ws;

  size_t ldsBytes = (size_t)LDS_FLOATS * sizeof(float);
  (void)hipFuncSetAttribute((const void*)kf_seq,
                            hipFuncAttributeMaxDynamicSharedMemorySize,
                            (int)ldsBytes);

  kf_seq<<<dim3(1), dim3(NTH), ldsBytes, stream>>>(y, A, C, Q, R, z0, P0, out, T, wsf, wsi);

  int nch = (T + LCH - 1) / LCH;
  kf_chunk<<<dim3(nch), dim3(512), 0, stream>>>(y, A, wsf, wsi, out, T);
  kf_ll<<<dim3(1), dim3(64), 0, stream>>>(wsf, wsi, out, T, nch);

  float* cov = out + (size_t)T * SD;
  kf_fill<<<dim3(T), dim3(256), 0, stream>>>(cov, wsi, T);
}